// Round 1
// baseline (423.969 us; speedup 1.0000x reference)
//
#include <hip/hip_runtime.h>

// YOLO loss: N=4096, S=14, B=2, NCLS=20.  Cells = 4096*14*14 = 802816.
//
// v2: coalesced-staging rewrite.
//  - pred (30 f32/cell, 120B stride) and tcls (20 f32/cell, 80B stride) were
//    loaded AoS-per-thread -> ~60-120 cache lines touched per VMEM instr ->
//    transaction-bound at 1.27 TB/s. Now staged via linear float4 loads
//    (1 KiB/wave/instr) into LDS padded to stride 31 / 21 floats per cell
//    (31*d % 32 == 0 and 21*d % 32 == 0 only at d=32 -> conflict-free reads).
//  - mask-layout detection fused into the main kernel: all blocks ballot over
//    the globally-shared first 1 KiB of the mask buffer (same semantics as the
//    old 16 KiB single-block scan; L2-resident broadcast).
//  - final scaling fused as a last-block-done epilogue (threadfence + counter
//    + device-scope atomic reads).  Launch chain: zero -> fused (was 4 kernels).
//  - per-cell math is bit-identical to the previous passing kernel (same op
//    order, same /14.0f, same shuffle reduction tree).

#define NCELLS (4096 * 14 * 14)
#define NBLOCKS (NCELLS / 256)   // 3136, exact

// ws layout: float[0..3] = cls, noobj, contain, reg sums; int slot 4 = block counter.

__global__ void yolo_zero_kernel(float* __restrict__ ws) {
    if (threadIdx.x < 16) ws[threadIdx.x] = 0.0f;
}

__global__ __launch_bounds__(256) void yolo_fused_kernel(
    const float* __restrict__ pred,
    const float* __restrict__ tbox,
    const float* __restrict__ tcls,
    const void* __restrict__ mask,
    float* __restrict__ ws,
    float* __restrict__ out) {
    __shared__ float sp[256 * 31];   // pred, padded stride 31 (31744 B)
    __shared__ float sc[256 * 21];   // tcls, padded stride 21 (21504 B)
    __shared__ float red[4][4];
    __shared__ int ired[4];

    const int t = threadIdx.x;
    const int lane = t & 63;
    const int wid = t >> 6;
    const int c0 = blockIdx.x << 8;  // first cell of this block
    const int c = c0 + t;

    // ---- mask layout detect: first 1 KiB, offsets !=0 mod 4 nonzero => bool8 ----
    {
        const unsigned int dv = ((const unsigned int*)mask)[t] & 0xFFFFFF00u;
        const unsigned long long bal = __ballot(dv != 0u);
        if (lane == 0) ired[wid] = (bal != 0ULL) ? 1 : 0;
    }

    // ---- tbox: stride-16B float4, already coalesced ----
    const float4 tb = ((const float4*)tbox)[c];

    // ---- stage pred: 1920 float4/block, linear -> padded LDS ----
    {
        const float4* p4 = (const float4*)(pred + (long long)c0 * 30);
#pragma unroll
        for (int i = 0; i < 8; ++i) {
            const int g = t + 256 * i;   // float4 index within block, < 1920
            if (g < 1920) {
                const float4 v = p4[g];
                const int j = 4 * g;         // float index
                const int q = j / 30;        // cell
                const int r = j - 30 * q;    // even, <= 28
                const int a = 31 * q + r;
                const int cr = (r == 28);    // v.z/v.w spill into next cell
                sp[a] = v.x;
                sp[a + 1] = v.y;
                sp[a + 2 + cr] = v.z;
                sp[a + 3 + cr] = v.w;
            }
        }
    }

    // ---- stage tcls: 1280 float4/block (20 % 4 == 0: no cell crossing) ----
    {
        const float4* c4 = (const float4*)(tcls + (long long)c0 * 20);
#pragma unroll
        for (int i = 0; i < 5; ++i) {
            const int g = t + 256 * i;       // < 1280, exact
            const float4 v = c4[g];
            const int q = g / 5;
            const int a = 21 * q + 4 * (g - 5 * q);
            sc[a] = v.x;
            sc[a + 1] = v.y;
            sc[a + 2] = v.z;
            sc[a + 3] = v.w;
        }
    }

    __syncthreads();

    const int mode = ired[0] | ired[1] | ired[2] | ired[3];
    float m;
    if (mode) {
        m = ((const unsigned char*)mask)[c] ? 1.0f : 0.0f;
    } else {
        m = ((const int*)mask)[c] ? 1.0f : 0.0f;
    }

    const float* pc = sp + 31 * t;   // this cell's 30 pred floats
    const float* cc = sc + 21 * t;   // this cell's 20 tcls floats

    // cls: m * sum((pred_cls - target_cls)^2)  (same order as before)
    float s = 0.0f;
#pragma unroll
    for (int i = 0; i < 20; ++i) {
        const float d = pc[10 + i] - cc[i];
        s += d * d;
    }
    float cls_s = m * s;

    float pv[10];
#pragma unroll
    for (int i = 0; i < 10; ++i) pv[i] = pc[i];

    const float conf0 = pv[4], conf1 = pv[9];
    float noobj_s = (1.0f - m) * (conf0 * conf0 + conf1 * conf1);

    // IoU per box
    float iou[2];
    const float at = (tb.z - tb.x) * (tb.w - tb.y);
#pragma unroll
    for (int b = 0; b < 2; ++b) {
        const int base = 5 * b;
        const float x = pv[base] / 14.0f;
        const float y = pv[base + 1] / 14.0f;
        const float w = pv[base + 2];
        const float h = pv[base + 3];
        const float p1x = x - w * 0.5f, p1y = y - h * 0.5f;
        const float p2x = x + w * 0.5f, p2y = y + h * 0.5f;
        const float ltx = fmaxf(p1x, tb.x), lty = fmaxf(p1y, tb.y);
        const float rbx = fminf(p2x, tb.z), rby = fminf(p2y, tb.w);
        const float iw = fmaxf(rbx - ltx, 0.0f), ih = fmaxf(rby - lty, 0.0f);
        const float inter = iw * ih;
        const float ap = w * h;
        iou[b] = inter / (ap + at - inter);
    }
    // jnp.argmax: first max wins -> pick box1 only if strictly greater
    const int best = (iou[1] > iou[0]) ? 5 : 0;
    const float bx = pv[best], by = pv[best + 1], bw = pv[best + 2],
                bh = pv[best + 3], bc = pv[best + 4];

    float contain_s = m * (bc - 1.0f) * (bc - 1.0f);

    const float dx = bx - tb.x, dy = by - tb.y;
    const float dw = sqrtf(bw) - sqrtf(tb.z);
    const float dh = sqrtf(bh) - sqrtf(tb.w);
    float reg_s = m * (dx * dx + dy * dy + dw * dw + dh * dh);

    // ---- reduction: wave64 shuffle -> LDS -> atomicAdd ----
#pragma unroll
    for (int off = 32; off > 0; off >>= 1) {
        cls_s += __shfl_down(cls_s, off, 64);
        noobj_s += __shfl_down(noobj_s, off, 64);
        contain_s += __shfl_down(contain_s, off, 64);
        reg_s += __shfl_down(reg_s, off, 64);
    }
    if (lane == 0) {
        red[wid][0] = cls_s;
        red[wid][1] = noobj_s;
        red[wid][2] = contain_s;
        red[wid][3] = reg_s;
    }
    __syncthreads();
    if (t < 4) {
        const float v = red[0][t] + red[1][t] + red[2][t] + red[3][t];
        atomicAdd(&ws[t], v);
    }

    // ---- last-block-done epilogue (replaces yolo_final_kernel) ----
    __threadfence();   // make this block's adds device-visible before counter bump
    if (t == 0) {
        const int done = atomicAdd((int*)ws + 4, 1);
        if (done == NBLOCKS - 1) {
            const float inv_n = 1.0f / 4096.0f;
            const float cls = atomicAdd(&ws[0], 0.0f) * inv_n;
            const float noobj = atomicAdd(&ws[1], 0.0f) * inv_n;
            const float contain = atomicAdd(&ws[2], 0.0f) * inv_n;
            const float reg = atomicAdd(&ws[3], 0.0f) * inv_n;
            out[0] = cls + 0.5f * noobj + 5.0f * reg + contain;
            out[1] = reg;
            out[2] = contain;
            out[3] = noobj;
            out[4] = cls;
        }
    }
}

extern "C" void kernel_launch(void* const* d_in, const int* in_sizes, int n_in,
                              void* d_out, int out_size, void* d_ws,
                              size_t ws_size, hipStream_t stream) {
    const float* pred = (const float*)d_in[0];
    const float* tbox = (const float*)d_in[1];
    const float* tcls = (const float*)d_in[2];
    const void* mask = d_in[3];
    float* ws = (float*)d_ws;
    float* out = (float*)d_out;

    yolo_zero_kernel<<<1, 64, 0, stream>>>(ws);
    yolo_fused_kernel<<<NBLOCKS, 256, 0, stream>>>(pred, tbox, tcls, mask, ws,
                                                   out);
}

// Round 2
// 317.249 us; speedup vs baseline: 1.3364x; 1.3364x over previous
//
#include <hip/hip_runtime.h>

// YOLO loss: N=4096, S=14, B=2, NCLS=20.  Cells = 4096*14*14 = 802816.
//
// v3: v2 minus the fence disaster.
//  - v2 post-mortem: __threadfence() in the fused epilogue lowers on gfx950
//    (multi-XCD) to buffer_wbl2+buffer_inv (full L2 writeback+invalidate),
//    executed once per WAVE = 12.5K serialized L2 flushes ~ 350 us. The
//    warm-cache rocprof replay (hbm_bytes=2e5) still took 328 us -> the fence,
//    not memory, was the whole regression.
//  - All cross-block communication is device-scope atomic RMWs (performed at
//    the coherence point, bypassing non-coherent per-XCD L2s). The only
//    ordering requirement -- a block's 4 sum-atomics complete before its
//    counter increment -- is satisfied with a per-wave `s_waitcnt vmcnt(0)`
//    (sums and counter are issued by the same wave). No L2 flush needed.
//  - Occupancy: 256-thread blocks at 53.8 KB LDS gave 2 blocks/CU (24%).
//    128-thread blocks halve LDS to 26.7 KB -> 6 blocks/CU (37.5%), same
//    per-thread work, better latency hiding.
//  - Coalesced staging kept from v2: pred/tcls loaded as linear float4
//    (1 KiB/wave/instr) into LDS padded to stride 31/21 floats per cell
//    (both coprime-ish with 32 -> 2 lanes/bank on reads = conflict-free).
//  - Per-cell math bit-identical to v1/v2 (both passed with absmax 0).

#define NCELLS (4096 * 14 * 14)
#define BLK 128
#define NBLOCKS (NCELLS / BLK)   // 6272, exact

// ws layout: float[0..3] = cls, noobj, contain, reg sums; int slot 4 = block counter.

__global__ void yolo_zero_kernel(float* __restrict__ ws) {
    if (threadIdx.x < 16) ws[threadIdx.x] = 0.0f;
}

__global__ __launch_bounds__(BLK) void yolo_fused_kernel(
    const float* __restrict__ pred,
    const float* __restrict__ tbox,
    const float* __restrict__ tcls,
    const void* __restrict__ mask,
    float* __restrict__ ws,
    float* __restrict__ out) {
    __shared__ float sp[BLK * 31];   // pred, padded stride 31 (15872 B)
    __shared__ float sc[BLK * 21];   // tcls, padded stride 21 (10752 B)
    __shared__ float red[2][4];
    __shared__ int ired[2];

    const int t = threadIdx.x;
    const int lane = t & 63;
    const int wid = t >> 6;
    const int c0 = blockIdx.x * BLK;  // first cell of this block
    const int c = c0 + t;

    // ---- mask layout detect: first 512 B; offsets !=0 mod 4 nonzero => bool8 ----
    {
        const unsigned int dv = ((const unsigned int*)mask)[t] & 0xFFFFFF00u;
        const unsigned long long bal = __ballot(dv != 0u);
        if (lane == 0) ired[wid] = (bal != 0ULL) ? 1 : 0;
    }

    // ---- tbox: stride-16B float4, already coalesced ----
    const float4 tb = ((const float4*)tbox)[c];

    // ---- stage pred: 960 float4/block, linear -> padded LDS ----
    {
        const float4* p4 = (const float4*)(pred + (long long)c0 * 30);
#pragma unroll
        for (int i = 0; i < 8; ++i) {
            const int g = t + BLK * i;   // float4 index within block, < 960
            if (g < 960) {
                const float4 v = p4[g];
                const int j = 4 * g;         // float index
                const int q = j / 30;        // cell
                const int r = j - 30 * q;    // even, <= 28
                const int a = 31 * q + r;
                const int cr = (r == 28);    // v.z/v.w spill into next cell
                sp[a] = v.x;
                sp[a + 1] = v.y;
                sp[a + 2 + cr] = v.z;
                sp[a + 3 + cr] = v.w;
            }
        }
    }

    // ---- stage tcls: 640 float4/block (20 % 4 == 0: no cell crossing) ----
    {
        const float4* c4 = (const float4*)(tcls + (long long)c0 * 20);
#pragma unroll
        for (int i = 0; i < 5; ++i) {
            const int g = t + BLK * i;       // < 640, exact
            const float4 v = c4[g];
            const int q = g / 5;
            const int a = 21 * q + 4 * (g - 5 * q);
            sc[a] = v.x;
            sc[a + 1] = v.y;
            sc[a + 2] = v.z;
            sc[a + 3] = v.w;
        }
    }

    __syncthreads();

    const int mode = ired[0] | ired[1];
    float m;
    if (mode) {
        m = ((const unsigned char*)mask)[c] ? 1.0f : 0.0f;
    } else {
        m = ((const int*)mask)[c] ? 1.0f : 0.0f;
    }

    const float* pc = sp + 31 * t;   // this cell's 30 pred floats
    const float* cc = sc + 21 * t;   // this cell's 20 tcls floats

    // cls: m * sum((pred_cls - target_cls)^2)  (same order as v1/v2)
    float s = 0.0f;
#pragma unroll
    for (int i = 0; i < 20; ++i) {
        const float d = pc[10 + i] - cc[i];
        s += d * d;
    }
    float cls_s = m * s;

    float pv[10];
#pragma unroll
    for (int i = 0; i < 10; ++i) pv[i] = pc[i];

    const float conf0 = pv[4], conf1 = pv[9];
    float noobj_s = (1.0f - m) * (conf0 * conf0 + conf1 * conf1);

    // IoU per box
    float iou[2];
    const float at = (tb.z - tb.x) * (tb.w - tb.y);
#pragma unroll
    for (int b = 0; b < 2; ++b) {
        const int base = 5 * b;
        const float x = pv[base] / 14.0f;
        const float y = pv[base + 1] / 14.0f;
        const float w = pv[base + 2];
        const float h = pv[base + 3];
        const float p1x = x - w * 0.5f, p1y = y - h * 0.5f;
        const float p2x = x + w * 0.5f, p2y = y + h * 0.5f;
        const float ltx = fmaxf(p1x, tb.x), lty = fmaxf(p1y, tb.y);
        const float rbx = fminf(p2x, tb.z), rby = fminf(p2y, tb.w);
        const float iw = fmaxf(rbx - ltx, 0.0f), ih = fmaxf(rby - lty, 0.0f);
        const float inter = iw * ih;
        const float ap = w * h;
        iou[b] = inter / (ap + at - inter);
    }
    // jnp.argmax: first max wins -> pick box1 only if strictly greater
    const int best = (iou[1] > iou[0]) ? 5 : 0;
    const float bx = pv[best], by = pv[best + 1], bw = pv[best + 2],
                bh = pv[best + 3], bc = pv[best + 4];

    float contain_s = m * (bc - 1.0f) * (bc - 1.0f);

    const float dx = bx - tb.x, dy = by - tb.y;
    const float dw = sqrtf(bw) - sqrtf(tb.z);
    const float dh = sqrtf(bh) - sqrtf(tb.w);
    float reg_s = m * (dx * dx + dy * dy + dw * dw + dh * dh);

    // ---- reduction: wave64 shuffle -> LDS -> atomicAdd ----
#pragma unroll
    for (int off = 32; off > 0; off >>= 1) {
        cls_s += __shfl_down(cls_s, off, 64);
        noobj_s += __shfl_down(noobj_s, off, 64);
        contain_s += __shfl_down(contain_s, off, 64);
        reg_s += __shfl_down(reg_s, off, 64);
    }
    if (lane == 0) {
        red[wid][0] = cls_s;
        red[wid][1] = noobj_s;
        red[wid][2] = contain_s;
        red[wid][3] = reg_s;
    }
    __syncthreads();
    if (t < 4) {
        const float v = red[0][t] + red[1][t];
        atomicAdd(&ws[t], v);
    }

    // ---- last-block-done epilogue (no __threadfence!) ----
    // The 4 sum-atomics above and the counter atomic below are issued by the
    // same wave (t<4 and t==0 are wave 0). A per-wave vmcnt(0) wait ensures
    // the device-scope sum-RMWs are performed at the coherence point before
    // the counter increment. All reads below are coherent-point RMWs too, so
    // no L2 writeback/invalidate is needed.
    asm volatile("s_waitcnt vmcnt(0)" ::: "memory");
    if (t == 0) {
        const int done = atomicAdd((int*)ws + 4, 1);
        if (done == NBLOCKS - 1) {
            const float inv_n = 1.0f / 4096.0f;
            const float cls = atomicAdd(&ws[0], 0.0f) * inv_n;
            const float noobj = atomicAdd(&ws[1], 0.0f) * inv_n;
            const float contain = atomicAdd(&ws[2], 0.0f) * inv_n;
            const float reg = atomicAdd(&ws[3], 0.0f) * inv_n;
            out[0] = cls + 0.5f * noobj + 5.0f * reg + contain;
            out[1] = reg;
            out[2] = contain;
            out[3] = noobj;
            out[4] = cls;
        }
    }
}

extern "C" void kernel_launch(void* const* d_in, const int* in_sizes, int n_in,
                              void* d_out, int out_size, void* d_ws,
                              size_t ws_size, hipStream_t stream) {
    const float* pred = (const float*)d_in[0];
    const float* tbox = (const float*)d_in[1];
    const float* tcls = (const float*)d_in[2];
    const void* mask = d_in[3];
    float* ws = (float*)d_ws;
    float* out = (float*)d_out;

    yolo_zero_kernel<<<1, 64, 0, stream>>>(ws);
    yolo_fused_kernel<<<NBLOCKS, BLK, 0, stream>>>(pred, tbox, tcls, mask, ws,
                                                   out);
}

// Round 3
// 230.624 us; speedup vs baseline: 1.8384x; 1.3756x over previous
//
#include <hip/hip_runtime.h>

// YOLO loss: N=4096, S=14, B=2, NCLS=20.  Cells = 4096*14*14 = 802816.
//
// v4: kill the atomic storm.
//  - Ladder post-mortem: v1 (70us), v3 (180us) were BOTH bound by same-cache-
//    line atomicAdd serialization at the coherence point (v1: 12.5K RMWs ~
//    70us; v3: 31.4K RMWs ~ 180us; warm-cache replays unchanged at 181us with
//    ~zero HBM traffic -> serialization, not memory). ~5.7ns per same-line RMW.
//  - Fix: grid-stride blocks (784 blocks x 8 tiles x 128 cells, exact cover),
//    per-thread register accumulation across tiles, ONE set of 4 atomics per
//    block, spread across 8 distinct cache lines (ws[16*(b&7)+k]); counter in
//    its own line. Total RMWs 31.4K -> 3.9K, per-line chain ~490 RMWs (~3us,
//    hidden by staggered block completion).
//  - Coalesced LDS staging kept from v3 (stride 31/21 padding, conflict-free).
//  - Epilogue ordering: sums and counter issued by the same wave; a per-wave
//    s_waitcnt vmcnt(0) orders them. No __threadfence (v2's 270us lesson:
//    it lowers to full L2 writeback+invalidate per wave on gfx950).
//  - Per-cell math bit-identical to v1/v2/v3 (all passed, absmax 0).

#define NCELLS (4096 * 14 * 14)
#define BLK 128
#define TPB 8                              // tiles per block
#define NB (NCELLS / (BLK * TPB))          // 784, exact

// ws layout (floats): lines j=0..7: ws[16j..16j+3] = cls,noobj,contain,reg
// partial sums for blocks with (b&7)==j.  int slot 128 (own line) = counter.

__global__ void yolo_zero_kernel(float* __restrict__ ws) {
    const int t = threadIdx.x;
    if (t < 144) ws[t] = 0.0f;   // 8 accumulator lines + counter line
}

__global__ __launch_bounds__(BLK) void yolo_fused_kernel(
    const float* __restrict__ pred,
    const float* __restrict__ tbox,
    const float* __restrict__ tcls,
    const void* __restrict__ mask,
    float* __restrict__ ws,
    float* __restrict__ out) {
    __shared__ float sp[BLK * 31];   // pred, padded stride 31 (15872 B)
    __shared__ float sc[BLK * 21];   // tcls, padded stride 21 (10752 B)
    __shared__ float red[2][4];
    __shared__ int ired[2];

    const int t = threadIdx.x;
    const int lane = t & 63;
    const int wid = t >> 6;

    // ---- mask layout detect (once): first 512 B of mask; any nonzero byte at
    // offset !=0 mod 4  =>  1-byte bool layout ----
    {
        const unsigned int dv = ((const unsigned int*)mask)[t] & 0xFFFFFF00u;
        const unsigned long long bal = __ballot(dv != 0u);
        if (lane == 0) ired[wid] = (bal != 0ULL) ? 1 : 0;
    }
    __syncthreads();
    const int mode = ired[0] | ired[1];

    float acc_cls = 0.0f, acc_noobj = 0.0f, acc_contain = 0.0f, acc_reg = 0.0f;

    for (int it = 0; it < TPB; ++it) {
        const int c0 = (blockIdx.x * TPB + it) * BLK;  // first cell of tile
        const int c = c0 + t;

        // ---- stage pred: 960 float4/tile, linear -> padded LDS ----
        {
            const float4* p4 = (const float4*)(pred + (long long)c0 * 30);
#pragma unroll
            for (int i = 0; i < 8; ++i) {
                const int g = t + BLK * i;   // float4 index within tile, < 960
                if (g < 960) {
                    const float4 v = p4[g];
                    const int j = 4 * g;         // float index
                    const int q = j / 30;        // cell within tile
                    const int r = j - 30 * q;    // even, <= 28
                    const int a = 31 * q + r;
                    const int cr = (r == 28);    // v.z/v.w spill into next cell
                    sp[a] = v.x;
                    sp[a + 1] = v.y;
                    sp[a + 2 + cr] = v.z;
                    sp[a + 3 + cr] = v.w;
                }
            }
        }

        // ---- stage tcls: 640 float4/tile (20 % 4 == 0: no cell crossing) ----
        {
            const float4* c4 = (const float4*)(tcls + (long long)c0 * 20);
#pragma unroll
            for (int i = 0; i < 5; ++i) {
                const int g = t + BLK * i;       // < 640, exact
                const float4 v = c4[g];
                const int q = g / 5;
                const int a = 21 * q + 4 * (g - 5 * q);
                sc[a] = v.x;
                sc[a + 1] = v.y;
                sc[a + 2] = v.z;
                sc[a + 3] = v.w;
            }
        }

        // ---- tbox + mask (coalesced) ----
        const float4 tb = ((const float4*)tbox)[c];
        float m;
        if (mode) {
            m = ((const unsigned char*)mask)[c] ? 1.0f : 0.0f;
        } else {
            m = ((const int*)mask)[c] ? 1.0f : 0.0f;
        }

        __syncthreads();

        const float* pc = sp + 31 * t;   // this cell's 30 pred floats
        const float* cc = sc + 21 * t;   // this cell's 20 tcls floats

        // cls: m * sum((pred_cls - target_cls)^2)  (same order as v1..v3)
        float s = 0.0f;
#pragma unroll
        for (int i = 0; i < 20; ++i) {
            const float d = pc[10 + i] - cc[i];
            s += d * d;
        }
        acc_cls += m * s;

        float pv[10];
#pragma unroll
        for (int i = 0; i < 10; ++i) pv[i] = pc[i];

        const float conf0 = pv[4], conf1 = pv[9];
        acc_noobj += (1.0f - m) * (conf0 * conf0 + conf1 * conf1);

        // IoU per box
        float iou[2];
        const float at = (tb.z - tb.x) * (tb.w - tb.y);
#pragma unroll
        for (int b = 0; b < 2; ++b) {
            const int base = 5 * b;
            const float x = pv[base] / 14.0f;
            const float y = pv[base + 1] / 14.0f;
            const float w = pv[base + 2];
            const float h = pv[base + 3];
            const float p1x = x - w * 0.5f, p1y = y - h * 0.5f;
            const float p2x = x + w * 0.5f, p2y = y + h * 0.5f;
            const float ltx = fmaxf(p1x, tb.x), lty = fmaxf(p1y, tb.y);
            const float rbx = fminf(p2x, tb.z), rby = fminf(p2y, tb.w);
            const float iw = fmaxf(rbx - ltx, 0.0f), ih = fmaxf(rby - lty, 0.0f);
            const float inter = iw * ih;
            const float ap = w * h;
            iou[b] = inter / (ap + at - inter);
        }
        // jnp.argmax: first max wins -> pick box1 only if strictly greater
        const int best = (iou[1] > iou[0]) ? 5 : 0;
        const float bx = pv[best], by = pv[best + 1], bw = pv[best + 2],
                    bh = pv[best + 3], bc = pv[best + 4];

        acc_contain += m * (bc - 1.0f) * (bc - 1.0f);

        const float dx = bx - tb.x, dy = by - tb.y;
        const float dw = sqrtf(bw) - sqrtf(tb.z);
        const float dh = sqrtf(bh) - sqrtf(tb.w);
        acc_reg += m * (dx * dx + dy * dy + dw * dw + dh * dh);

        __syncthreads();   // before next iteration overwrites LDS
    }

    // ---- reduction: wave64 shuffle -> LDS -> one atomic set per block ----
#pragma unroll
    for (int off = 32; off > 0; off >>= 1) {
        acc_cls += __shfl_down(acc_cls, off, 64);
        acc_noobj += __shfl_down(acc_noobj, off, 64);
        acc_contain += __shfl_down(acc_contain, off, 64);
        acc_reg += __shfl_down(acc_reg, off, 64);
    }
    if (lane == 0) {
        red[wid][0] = acc_cls;
        red[wid][1] = acc_noobj;
        red[wid][2] = acc_contain;
        red[wid][3] = acc_reg;
    }
    __syncthreads();
    const int line = 16 * (blockIdx.x & 7);   // spread over 8 cache lines
    if (t < 4) {
        const float v = red[0][t] + red[1][t];
        atomicAdd(&ws[line + t], v);
    }

    // ---- last-block-done epilogue (same-wave vmcnt ordering, no fence) ----
    asm volatile("s_waitcnt vmcnt(0)" ::: "memory");
    if (t == 0) {
        const int done = atomicAdd((int*)ws + 128, 1);
        if (done == NB - 1) {
            float sum[4];
#pragma unroll
            for (int k = 0; k < 4; ++k) {
                float v = 0.0f;
#pragma unroll
                for (int j = 0; j < 8; ++j) v += atomicAdd(&ws[16 * j + k], 0.0f);
                sum[k] = v;
            }
            const float inv_n = 1.0f / 4096.0f;
            const float cls = sum[0] * inv_n;
            const float noobj = sum[1] * inv_n;
            const float contain = sum[2] * inv_n;
            const float reg = sum[3] * inv_n;
            out[0] = cls + 0.5f * noobj + 5.0f * reg + contain;
            out[1] = reg;
            out[2] = contain;
            out[3] = noobj;
            out[4] = cls;
        }
    }
}

extern "C" void kernel_launch(void* const* d_in, const int* in_sizes, int n_in,
                              void* d_out, int out_size, void* d_ws,
                              size_t ws_size, hipStream_t stream) {
    const float* pred = (const float*)d_in[0];
    const float* tbox = (const float*)d_in[1];
    const float* tcls = (const float*)d_in[2];
    const void* mask = d_in[3];
    float* ws = (float*)d_ws;
    float* out = (float*)d_out;

    yolo_zero_kernel<<<1, 256, 0, stream>>>(ws);
    yolo_fused_kernel<<<NB, BLK, 0, stream>>>(pred, tbox, tcls, mask, ws, out);
}

// Round 4
// 203.045 us; speedup vs baseline: 2.0881x; 1.1358x over previous
//
#include <hip/hip_runtime.h>

// YOLO loss: N=4096, S=14, B=2, NCLS=20.  Cells = 4096*14*14 = 802816.
//
// v5: fix exposed-latency regime (v4 post-mortem).
//  - v4 was 95us at 14% occupancy: grid of 784 blocks = 6 waves/CU (1.5/SIMD,
//    no TLP), and reg-round-trip staging at VGPR=68 couldn't keep 13 loads in
//    flight -> ~9.3K cy per 128-cell tile, all exposed latency. VALU total was
//    only ~7us; HBM floor ~14us. Latency-bound, not BW/transaction-bound.
//  - Fix 1: __builtin_amdgcn_global_load_lds width=16 for pred+tcls staging:
//    fire-and-forget global->LDS DMA, no VGPR round-trip, all 13 chunk-loads
//    per thread issue back-to-back (full memory-level parallelism).
//  - Fix 2: 3136 blocks x 256 threads, one cell/thread, no tile loop.
//    LDS = 50KB -> 3 blocks/CU = 12 waves/CU resident, 12.25 rounds.
//  - Cost: global_load_lds writes LINEAR LDS (wave-uniform base + lane*16;
//    no padding possible) -> stride-30/20 reads are 4-way/8-way bank
//    conflicted. Second-order (~6us LDS pipe) vs the latency win.
//  - Atomic discipline kept from v4 (its one confirmed win): 4 RMWs per block
//    spread across 64 cache lines (196 RMWs/line, lines parallel). Mask-layout
//    detect is per-wave ballot over 256B of the first 1KB (wave-uniform, no
//    LDS, no barrier; P(wrong) ~ 2^-144). Final scaling in a tiny 4th-..3rd
//    kernel -- no device-wide counter chain, no fences (v2 lesson).
//  - Per-cell math bit-identical to v1..v4 (all passed, absmax 0).

#define NCELLS (4096 * 14 * 14)
#define BLK 256
#define NB (NCELLS / BLK)   // 3136, exact
#define NLINES 64           // partial-sum cache lines in ws (64 x 64B = 4KB)

typedef const __attribute__((address_space(1))) void* gas_t;
typedef __attribute__((address_space(3))) void* las_t;

__device__ __forceinline__ void gload_lds16(const void* g, void* l) {
    // per-lane global src; wave-uniform LDS dst (HW adds lane*16)
    __builtin_amdgcn_global_load_lds((gas_t)g, (las_t)l, 16, 0, 0);
}

__global__ void yolo_zero_kernel(float* __restrict__ ws) {
    ((float4*)ws)[threadIdx.x] = make_float4(0.f, 0.f, 0.f, 0.f);  // 256 thr * 16B = 4KB
}

__global__ __launch_bounds__(BLK) void yolo_main_kernel(
    const float* __restrict__ pred,
    const float* __restrict__ tbox,
    const float* __restrict__ tcls,
    const void* __restrict__ mask,
    float* __restrict__ ws) {
    __shared__ float sp[BLK * 30];   // linear pred (30720 B)
    __shared__ float sc[BLK * 20];   // linear tcls (20480 B)
    __shared__ float red[4][4];

    const int t = threadIdx.x;
    const int lane = t & 63;
    const int wid = t >> 6;
    const int c0 = blockIdx.x * BLK;
    const int c = c0 + t;

    // ---- stage pred: 1920 16B chunks, direct-to-LDS, fire-and-forget ----
    {
        const char* pb = (const char*)(pred + (long long)c0 * 30);
        char* spb = (char*)sp;
#pragma unroll
        for (int i = 0; i < 7; ++i) {
            const int k0 = i * 256 + wid * 64;   // uniform chunk base per wave
            gload_lds16(pb + 16 * (k0 + lane), spb + 16 * k0);
        }
        if (wid < 2) {                            // wave-uniform tail: 128 chunks
            const int k0 = 1792 + wid * 64;
            gload_lds16(pb + 16 * (k0 + lane), spb + 16 * k0);
        }
    }
    // ---- stage tcls: 1280 16B chunks ----
    {
        const char* cb = (const char*)(tcls + (long long)c0 * 20);
        char* scb = (char*)sc;
#pragma unroll
        for (int i = 0; i < 5; ++i) {
            const int k0 = i * 256 + wid * 64;
            gload_lds16(cb + 16 * (k0 + lane), scb + 16 * k0);
        }
    }

    // ---- per-wave mask layout detect (first 1KB; bytes at off%4!=0 nonzero
    // => 1-byte bool layout). Wave-uniform, no barrier needed. ----
    const unsigned int dv = ((const unsigned int*)mask)[t] & 0xFFFFFF00u;
    const unsigned long long bal = __ballot(dv != 0u);
    const int mode = (bal != 0ULL) ? 1 : 0;

    // ---- tbox + mask (coalesced; overlap with in-flight LDS loads) ----
    const float4 tb = ((const float4*)tbox)[c];
    float m;
    if (mode) {
        m = ((const unsigned char*)mask)[c] ? 1.0f : 0.0f;
    } else {
        m = ((const int*)mask)[c] ? 1.0f : 0.0f;
    }

    asm volatile("s_waitcnt vmcnt(0)" ::: "memory");  // LDS-DMA complete
    __syncthreads();

    const float* pc = sp + 30 * t;   // this cell's 30 pred floats
    const float* cc = sc + 20 * t;   // this cell's 20 tcls floats

    // cls: m * sum((pred_cls - target_cls)^2)  (same order as v1..v4)
    float s = 0.0f;
#pragma unroll
    for (int i = 0; i < 20; ++i) {
        const float d = pc[10 + i] - cc[i];
        s += d * d;
    }
    float cls_s = m * s;

    float pv[10];
#pragma unroll
    for (int i = 0; i < 10; ++i) pv[i] = pc[i];

    const float conf0 = pv[4], conf1 = pv[9];
    float noobj_s = (1.0f - m) * (conf0 * conf0 + conf1 * conf1);

    // IoU per box
    float iou[2];
    const float at = (tb.z - tb.x) * (tb.w - tb.y);
#pragma unroll
    for (int b = 0; b < 2; ++b) {
        const int base = 5 * b;
        const float x = pv[base] / 14.0f;
        const float y = pv[base + 1] / 14.0f;
        const float w = pv[base + 2];
        const float h = pv[base + 3];
        const float p1x = x - w * 0.5f, p1y = y - h * 0.5f;
        const float p2x = x + w * 0.5f, p2y = y + h * 0.5f;
        const float ltx = fmaxf(p1x, tb.x), lty = fmaxf(p1y, tb.y);
        const float rbx = fminf(p2x, tb.z), rby = fminf(p2y, tb.w);
        const float iw = fmaxf(rbx - ltx, 0.0f), ih = fmaxf(rby - lty, 0.0f);
        const float inter = iw * ih;
        const float ap = w * h;
        iou[b] = inter / (ap + at - inter);
    }
    // jnp.argmax: first max wins -> pick box1 only if strictly greater
    const int best = (iou[1] > iou[0]) ? 5 : 0;
    const float bx = pv[best], by = pv[best + 1], bw = pv[best + 2],
                bh = pv[best + 3], bc = pv[best + 4];

    float contain_s = m * (bc - 1.0f) * (bc - 1.0f);

    const float dx = bx - tb.x, dy = by - tb.y;
    const float dw = sqrtf(bw) - sqrtf(tb.z);
    const float dh = sqrtf(bh) - sqrtf(tb.w);
    float reg_s = m * (dx * dx + dy * dy + dw * dw + dh * dh);

    // ---- reduction: wave64 shuffle -> LDS -> 4 atomics per block ----
#pragma unroll
    for (int off = 32; off > 0; off >>= 1) {
        cls_s += __shfl_down(cls_s, off, 64);
        noobj_s += __shfl_down(noobj_s, off, 64);
        contain_s += __shfl_down(contain_s, off, 64);
        reg_s += __shfl_down(reg_s, off, 64);
    }
    if (lane == 0) {
        red[wid][0] = cls_s;
        red[wid][1] = noobj_s;
        red[wid][2] = contain_s;
        red[wid][3] = reg_s;
    }
    __syncthreads();
    if (t < 4) {
        const float v = red[0][t] + red[1][t] + red[2][t] + red[3][t];
        atomicAdd(&ws[16 * (blockIdx.x & (NLINES - 1)) + t], v);
    }
}

__global__ void yolo_final_kernel(const float* __restrict__ ws,
                                  float* __restrict__ out) {
    const int t = threadIdx.x;   // 64 threads, one partial line each
    float4 v = ((const float4*)ws)[4 * t];   // line t: ws[16t .. 16t+3]
#pragma unroll
    for (int off = 32; off > 0; off >>= 1) {
        v.x += __shfl_down(v.x, off, 64);
        v.y += __shfl_down(v.y, off, 64);
        v.z += __shfl_down(v.z, off, 64);
        v.w += __shfl_down(v.w, off, 64);
    }
    if (t == 0) {
        const float inv_n = 1.0f / 4096.0f;
        const float cls = v.x * inv_n;
        const float noobj = v.y * inv_n;
        const float contain = v.z * inv_n;
        const float reg = v.w * inv_n;
        out[0] = cls + 0.5f * noobj + 5.0f * reg + contain;
        out[1] = reg;
        out[2] = contain;
        out[3] = noobj;
        out[4] = cls;
    }
}

extern "C" void kernel_launch(void* const* d_in, const int* in_sizes, int n_in,
                              void* d_out, int out_size, void* d_ws,
                              size_t ws_size, hipStream_t stream) {
    const float* pred = (const float*)d_in[0];
    const float* tbox = (const float*)d_in[1];
    const float* tcls = (const float*)d_in[2];
    const void* mask = d_in[3];
    float* ws = (float*)d_ws;
    float* out = (float*)d_out;

    yolo_zero_kernel<<<1, 256, 0, stream>>>(ws);
    yolo_main_kernel<<<NB, BLK, 0, stream>>>(pred, tbox, tcls, mask, ws);
    yolo_final_kernel<<<1, 64, 0, stream>>>(ws, out);
}